// Round 1
// baseline (500.577 us; speedup 1.0000x reference)
//
#include <hip/hip_runtime.h>
#include <stdint.h>

#define H 32
#define HKV 8
#define D 128
#define SQ 1024
#define CTX 3072
#define SKV 4096
#define FP8_MAX_C 448.0f
#define EPS_C 1e-8f

typedef __attribute__((ext_vector_type(4))) float f32x4;
typedef __attribute__((ext_vector_type(8))) __bf16 bf16x8;
typedef __attribute__((ext_vector_type(8))) unsigned short ushort8;

__device__ __forceinline__ unsigned short f2bf(float x) {
  unsigned int u = __builtin_bit_cast(unsigned int, x);
  u += 0x7fffu + ((u >> 16) & 1u);
  return (unsigned short)(u >> 16);
}

__device__ __forceinline__ f32x4 mfma16(bf16x8 a, bf16x8 b, f32x4 c) {
  return __builtin_amdgcn_mfma_f32_16x16x32_bf16(a, b, c, 0, 0, 0);
}

// ---- kernel 1: per-kv-head absmax scales; blocks 0-7 -> k, 8-15 -> v ----
__global__ void scales_kernel(const float* __restrict__ k,
                              const float* __restrict__ v,
                              float* __restrict__ scales) {
  const int b = blockIdx.x;
  const float* src = (b < HKV) ? k : v;
  const int h = b & 7;
  const int tid = threadIdx.x;  // 256
  const int d0 = (tid & 31) * 4;
  float mx = 0.f;
  for (int t = tid >> 5; t < SQ; t += 8) {
    float4 vv = *reinterpret_cast<const float4*>(src + (size_t)t * (HKV * D) + h * D + d0);
    mx = fmaxf(mx, fmaxf(fmaxf(fabsf(vv.x), fabsf(vv.y)),
                         fmaxf(fabsf(vv.z), fabsf(vv.w))));
  }
  __shared__ float red[256];
  red[tid] = mx;
  __syncthreads();
  for (int s = 128; s > 0; s >>= 1) {
    if (tid < s) red[tid] = fmaxf(red[tid], red[tid + s]);
    __syncthreads();
  }
  if (tid == 0) scales[b] = fmaxf(red[0] / FP8_MAX_C, EPS_C);
}

// ---- kernel 2: k_comb[h][t][d] bf16 (ctx: cache*k_scale, new: raw k) ----
__global__ void prep_k(const float* __restrict__ k,
                       const float* __restrict__ k_cache,
                       const int* __restrict__ cache_slots,
                       const float* __restrict__ scales,
                       unsigned short* __restrict__ k_comb) {
  const int tid = blockIdx.x * 256 + threadIdx.x;  // 524288
  const int d8 = tid & 15;
  const int t = (tid >> 4) & (SKV - 1);
  const int h = tid >> 16;
  const int d0 = d8 * 8;
  const float* src;
  float mul;
  if (t < CTX) {
    int slot = cache_slots[t];
    src = k_cache + (size_t)slot * (HKV * D) + h * D + d0;
    mul = scales[h];
  } else {
    src = k + (size_t)(t - CTX) * (HKV * D) + h * D + d0;
    mul = 1.f;
  }
  float4 a = *reinterpret_cast<const float4*>(src);
  float4 bb = *reinterpret_cast<const float4*>(src + 4);
  ushort8 r;
  r[0] = f2bf(a.x * mul);  r[1] = f2bf(a.y * mul);
  r[2] = f2bf(a.z * mul);  r[3] = f2bf(a.w * mul);
  r[4] = f2bf(bb.x * mul); r[5] = f2bf(bb.y * mul);
  r[6] = f2bf(bb.z * mul); r[7] = f2bf(bb.w * mul);
  *reinterpret_cast<ushort8*>(k_comb + ((size_t)h * SKV + t) * D + d0) = r;
}

// ---- kernel 3: v_combT[h][d][t] bf16 (transposed for PV fragments) ----
__global__ void prep_v(const float* __restrict__ v,
                       const float* __restrict__ v_cache,
                       const int* __restrict__ cache_slots,
                       const float* __restrict__ scales,
                       unsigned short* __restrict__ v_combT) {
  const int tid = blockIdx.x * 256 + threadIdx.x;  // 524288
  const int d = tid & 127;
  const int t8 = (tid >> 7) & 511;
  const int h = tid >> 16;
  const int t0 = t8 * 8;
  const float sc = scales[8 + h];
  ushort8 r;
#pragma unroll
  for (int i = 0; i < 8; ++i) {
    int t = t0 + i;
    float val;
    if (t < CTX) {
      int slot = cache_slots[t];
      val = v_cache[(size_t)slot * (HKV * D) + h * D + d] * sc;
    } else {
      val = v[(size_t)(t - CTX) * (HKV * D) + h * D + d];
    }
    r[i] = f2bf(val);
  }
  *reinterpret_cast<ushort8*>(v_combT + ((size_t)h * D + d) * SKV + t0) = r;
}

// ---- kernel 4: flash attention, 4 waves/block = 4 q-heads of one kv-head ----
__launch_bounds__(256, 2)
__global__ void attn_kernel(const float* __restrict__ q,
                            const unsigned short* __restrict__ k_comb,
                            const unsigned short* __restrict__ v_combT,
                            float* __restrict__ out) {
  const int bid = blockIdx.x;
  const int qt = bid & 63;
  const int hkv = bid >> 6;
  const int wid = threadIdx.x >> 6;
  const int l = threadIdx.x & 63;
  const int lo = l & 15;
  const int g = l >> 4;
  const int hq = hkv * 4 + wid;
  const int qbase = qt * 16;
  const int nt = 97 + (qt >> 1);  // 96 ctx tiles + (qblk+1) new tiles

  // Q fragments, pre-scaled by SCALE*log2(e) so softmax is exp2-based
  bf16x8 qf[4];
  {
    const float qs = 0.088388347648318447f * 1.4426950408889634f;
    const float* qp = q + (size_t)(qbase + lo) * (H * D) + hq * D;
#pragma unroll
    for (int ks = 0; ks < 4; ++ks) {
      int d0 = ks * 32 + g * 8;
      float4 a = *reinterpret_cast<const float4*>(qp + d0);
      float4 b = *reinterpret_cast<const float4*>(qp + d0 + 4);
      union { unsigned short u[8]; bf16x8 v; } f;
      f.u[0] = f2bf(a.x * qs); f.u[1] = f2bf(a.y * qs);
      f.u[2] = f2bf(a.z * qs); f.u[3] = f2bf(a.w * qs);
      f.u[4] = f2bf(b.x * qs); f.u[5] = f2bf(b.y * qs);
      f.u[6] = f2bf(b.z * qs); f.u[7] = f2bf(b.w * qs);
      qf[ks] = f.v;
    }
  }

  f32x4 acc[8];
#pragma unroll
  for (int dt = 0; dt < 8; ++dt) acc[dt] = (f32x4){0.f, 0.f, 0.f, 0.f};
  float mrow[4] = {-__builtin_inff(), -__builtin_inff(),
                   -__builtin_inff(), -__builtin_inff()};
  float lrow[4] = {0.f, 0.f, 0.f, 0.f};

  __shared__ __align__(16) unsigned short p_lds[4][16][40];

  const unsigned short* kb = k_comb + (size_t)hkv * SKV * D;
  const unsigned short* vb = v_combT + (size_t)hkv * D * SKV;

  for (int tile = 0; tile < nt; ++tile) {
    const int tb = tile * 32;
    f32x4 s0 = (f32x4){0.f, 0.f, 0.f, 0.f};
    f32x4 s1 = (f32x4){0.f, 0.f, 0.f, 0.f};
    {
      const unsigned short* kp0 = kb + (size_t)(tb + lo) * D + g * 8;
#pragma unroll
      for (int ks = 0; ks < 4; ++ks) {
        bf16x8 k0 = *reinterpret_cast<const bf16x8*>(kp0 + ks * 32);
        bf16x8 k1 = *reinterpret_cast<const bf16x8*>(kp0 + 16 * D + ks * 32);
        s0 = mfma16(qf[ks], k0, s0);
        s1 = mfma16(qf[ks], k1, s1);
      }
    }
    // online softmax (rows 4g+r live in the 16 lanes sharing g)
    float p0[4], p1[4];
#pragma unroll
    for (int r = 0; r < 4; ++r) {
      float mx = fmaxf(s0[r], s1[r]);
      mx = fmaxf(mx, __shfl_xor(mx, 1));
      mx = fmaxf(mx, __shfl_xor(mx, 2));
      mx = fmaxf(mx, __shfl_xor(mx, 4));
      mx = fmaxf(mx, __shfl_xor(mx, 8));
      float mn = fmaxf(mrow[r], mx);
      float scl = __builtin_amdgcn_exp2f(mrow[r] - mn);
      mrow[r] = mn;
      p0[r] = __builtin_amdgcn_exp2f(s0[r] - mn);
      p1[r] = __builtin_amdgcn_exp2f(s1[r] - mn);
      float rs = p0[r] + p1[r];
      rs += __shfl_xor(rs, 1);
      rs += __shfl_xor(rs, 2);
      rs += __shfl_xor(rs, 4);
      rs += __shfl_xor(rs, 8);
      lrow[r] = lrow[r] * scl + rs;
#pragma unroll
      for (int dt = 0; dt < 8; ++dt) acc[dt][r] *= scl;
    }
    // P -> LDS (C/D layout) -> A-fragment layout
#pragma unroll
    for (int r = 0; r < 4; ++r) {
      p_lds[wid][g * 4 + r][lo] = f2bf(p0[r]);
      p_lds[wid][g * 4 + r][16 + lo] = f2bf(p1[r]);
    }
    __syncthreads();
    bf16x8 pf = *reinterpret_cast<const bf16x8*>(&p_lds[wid][lo][g * 8]);
    {
      const unsigned short* vp = vb + (size_t)lo * SKV + tb + g * 8;
#pragma unroll
      for (int dt = 0; dt < 8; ++dt) {
        bf16x8 vf = *reinterpret_cast<const bf16x8*>(vp + (size_t)dt * 16 * SKV);
        acc[dt] = mfma16(pf, vf, acc[dt]);
      }
    }
    __syncthreads();
  }

#pragma unroll
  for (int r = 0; r < 4; ++r) {
    float inv = 1.f / lrow[r];
    float* op = out + (size_t)(qbase + g * 4 + r) * (H * D) + hq * D + lo;
#pragma unroll
    for (int dt = 0; dt < 8; ++dt) op[dt * 16] = acc[dt][r] * inv;
  }
}

extern "C" void kernel_launch(void* const* d_in, const int* in_sizes, int n_in,
                              void* d_out, int out_size, void* d_ws, size_t ws_size,
                              hipStream_t stream) {
  (void)in_sizes; (void)n_in; (void)out_size; (void)ws_size;
  const float* q = (const float*)d_in[0];
  const float* k = (const float*)d_in[1];
  const float* v = (const float*)d_in[2];
  const float* k_cache = (const float*)d_in[3];
  const float* v_cache = (const float*)d_in[4];
  const int* cache_slots = (const int*)d_in[6];
  float* out = (float*)d_out;

  float* scales = (float*)d_ws;                               // 16 floats
  unsigned short* k_comb = (unsigned short*)((char*)d_ws + 256);  // 8 MB
  unsigned short* v_combT = k_comb + (size_t)HKV * SKV * D;       // 8 MB

  scales_kernel<<<16, 256, 0, stream>>>(k, v, scales);
  prep_k<<<2048, 256, 0, stream>>>(k, k_cache, cache_slots, scales, k_comb);
  prep_v<<<2048, 256, 0, stream>>>(v, v_cache, cache_slots, scales, v_combT);
  attn_kernel<<<512, 256, 0, stream>>>(q, k_comb, v_combT, out);
}

// Round 3
// 466.349 us; speedup vs baseline: 1.0734x; 1.0734x over previous
//
#include <hip/hip_runtime.h>
#include <stdint.h>

#define H 32
#define HKV 8
#define D 128
#define SQ 1024
#define CTX 3072
#define SKV 4096
#define FP8_MAX_C 448.0f
#define EPS_C 1e-8f

typedef __attribute__((ext_vector_type(4))) float f32x4;
typedef __attribute__((ext_vector_type(8))) __bf16 bf16x8;
typedef __attribute__((ext_vector_type(8))) unsigned short u16x8;
typedef __attribute__((ext_vector_type(4))) unsigned short u16x4;

__device__ __forceinline__ unsigned short f2bf(float x) {
  unsigned int u = __builtin_bit_cast(unsigned int, x);
  u += 0x7fffu + ((u >> 16) & 1u);
  return (unsigned short)(u >> 16);
}

__device__ __forceinline__ f32x4 mfma16(bf16x8 a, bf16x8 b, f32x4 c) {
  return __builtin_amdgcn_mfma_f32_16x16x32_bf16(a, b, c, 0, 0, 0);
}

// ---- kernel 1: per-kv-head absmax scales; blocks 0-7 -> k, 8-15 -> v ----
__global__ void scales_kernel(const float* __restrict__ k,
                              const float* __restrict__ v,
                              float* __restrict__ scales) {
  const int b = blockIdx.x;
  const float* src = (b < HKV) ? k : v;
  const int h = b & 7;
  const int tid = threadIdx.x;  // 256
  const int d0 = (tid & 31) * 4;
  float mx = 0.f;
  for (int t = tid >> 5; t < SQ; t += 8) {
    float4 vv = *reinterpret_cast<const float4*>(src + (size_t)t * (HKV * D) + h * D + d0);
    mx = fmaxf(mx, fmaxf(fmaxf(fabsf(vv.x), fabsf(vv.y)),
                         fmaxf(fabsf(vv.z), fabsf(vv.w))));
  }
  __shared__ float red[256];
  red[tid] = mx;
  __syncthreads();
  for (int s = 128; s > 0; s >>= 1) {
    if (tid < s) red[tid] = fmaxf(red[tid], red[tid + s]);
    __syncthreads();
  }
  if (tid == 0) scales[b] = fmaxf(red[0] / FP8_MAX_C, EPS_C);
}

// ---- kernel 2: k_comb[h][t][d] bf16 (ctx: cache*k_scale, new: raw k) ----
__global__ void prep_k(const float* __restrict__ k,
                       const float* __restrict__ k_cache,
                       const int* __restrict__ cache_slots,
                       const float* __restrict__ scales,
                       unsigned short* __restrict__ k_comb) {
  const int tid = blockIdx.x * 256 + threadIdx.x;  // 524288
  const int d8 = tid & 15;
  const int t = (tid >> 4) & (SKV - 1);
  const int h = tid >> 16;
  const int d0 = d8 * 8;
  const float* src;
  float mul;
  if (t < CTX) {
    int slot = cache_slots[t];
    src = k_cache + (size_t)slot * (HKV * D) + h * D + d0;
    mul = scales[h];
  } else {
    src = k + (size_t)(t - CTX) * (HKV * D) + h * D + d0;
    mul = 1.f;
  }
  float4 a = *reinterpret_cast<const float4*>(src);
  float4 bb = *reinterpret_cast<const float4*>(src + 4);
  u16x8 r;
  r[0] = f2bf(a.x * mul);  r[1] = f2bf(a.y * mul);
  r[2] = f2bf(a.z * mul);  r[3] = f2bf(a.w * mul);
  r[4] = f2bf(bb.x * mul); r[5] = f2bf(bb.y * mul);
  r[6] = f2bf(bb.z * mul); r[7] = f2bf(bb.w * mul);
  *reinterpret_cast<u16x8*>(k_comb + ((size_t)h * SKV + t) * D + d0) = r;
}

// ---- kernel 3: v_combT[h][d][t] bf16 (transposed for PV fragments) ----
__global__ void prep_v(const float* __restrict__ v,
                       const float* __restrict__ v_cache,
                       const int* __restrict__ cache_slots,
                       const float* __restrict__ scales,
                       unsigned short* __restrict__ v_combT) {
  const int tid = blockIdx.x * 256 + threadIdx.x;  // 524288
  const int d = tid & 127;
  const int t8 = (tid >> 7) & 511;
  const int h = tid >> 16;
  const int t0 = t8 * 8;
  const float sc = scales[8 + h];
  u16x8 r;
#pragma unroll
  for (int i = 0; i < 8; ++i) {
    int t = t0 + i;
    float val;
    if (t < CTX) {
      int slot = cache_slots[t];
      val = v_cache[(size_t)slot * (HKV * D) + h * D + d] * sc;
    } else {
      val = v[(size_t)(t - CTX) * (HKV * D) + h * D + d];
    }
    r[i] = f2bf(val);
  }
  *reinterpret_cast<u16x8*>(v_combT + ((size_t)h * D + d) * SKV + t0) = r;
}

// ---- kernel 4: flash attention, swapped-QK^T, KVBLK=64, no barriers ----
__launch_bounds__(256, 2)
__global__ void attn_kernel(const float* __restrict__ q,
                            const unsigned short* __restrict__ k_comb,
                            const unsigned short* __restrict__ v_combT,
                            float* __restrict__ out) {
  const int bid = blockIdx.x;
  const int hkv = bid & 7;   // XCD-aware: all blocks of one kv-head on one XCD
  const int qt = bid >> 3;   // 0..63
  const int wid = threadIdx.x >> 6;
  const int l = threadIdx.x & 63;
  const int lo = l & 15;
  const int g = l >> 4;
  const int hq = hkv * 4 + wid;
  const int qbase = qt * 16;
  const int nt32 = 97 + (qt >> 1);
  const int n64 = (nt32 + 1) >> 1;
  const bool odd = (nt32 & 1) != 0;

  // Q fragments (B-operand), pre-scaled by SCALE*log2(e) for exp2 softmax
  bf16x8 qf[4];
  {
    const float qs = 0.088388347648318447f * 1.4426950408889634f;
    const float* qp = q + (size_t)(qbase + lo) * (H * D) + hq * D;
#pragma unroll
    for (int ks = 0; ks < 4; ++ks) {
      int d0 = ks * 32 + g * 8;
      float4 a = *reinterpret_cast<const float4*>(qp + d0);
      float4 b = *reinterpret_cast<const float4*>(qp + d0 + 4);
      union { unsigned short u[8]; bf16x8 v; } f;
      f.u[0] = f2bf(a.x * qs); f.u[1] = f2bf(a.y * qs);
      f.u[2] = f2bf(a.z * qs); f.u[3] = f2bf(a.w * qs);
      f.u[4] = f2bf(b.x * qs); f.u[5] = f2bf(b.y * qs);
      f.u[6] = f2bf(b.z * qs); f.u[7] = f2bf(b.w * qs);
      qf[ks] = f.v;
    }
  }

  f32x4 acc[8];
#pragma unroll
  for (int dt = 0; dt < 8; ++dt) acc[dt] = (f32x4){0.f, 0.f, 0.f, 0.f};
  float m = -1e30f;   // running max (log2 units), per q-row (q = lo)
  float lsum = 0.f;   // running denom, per q-row

  // per-wave P bounce buffer: [q=16][kv=64] padded to 72 (16B-aligned rows)
  __shared__ __align__(16) unsigned short p_lds[4][16][72];

  const unsigned short* kb = k_comb + (size_t)hkv * SKV * D;
  const unsigned short* vb = v_combT + (size_t)hkv * D * SKV;

  // K fragment loader: kf[sf*4+ks] = K[tb+16sf+lo][g*8+ks*32 .. +8]
  auto loadK = [&](int tb, bf16x8* kf) {
    const unsigned short* kp = kb + (size_t)(tb + lo) * D + g * 8;
#pragma unroll
    for (int sf = 0; sf < 4; ++sf)
#pragma unroll
      for (int ks = 0; ks < 4; ++ks)
        kf[sf * 4 + ks] = *reinterpret_cast<const bf16x8*>(kp + (size_t)sf * 16 * D + ks * 32);
  };

  bf16x8 kf[16], kn[16];
  loadK(0, kf);

  for (int t = 0; t < n64; ++t) {
    const int tb = t * 64;

    // ---- QK^T swapped: s[sf] = S^T[kv-subtile sf][q]  (kv rows, q cols) ----
    f32x4 s[4];
#pragma unroll
    for (int sf = 0; sf < 4; ++sf) {
      s[sf] = (f32x4){0.f, 0.f, 0.f, 0.f};
#pragma unroll
      for (int ks = 0; ks < 4; ++ks)
        s[sf] = mfma16(kf[sf * 4 + ks], qf[ks], s[sf]);
    }

    // ---- prefetch next K tile (hidden under softmax+PV) ----
    if (t + 1 < n64) loadK(tb + 64, kn);

    // ---- preload V fragments for this tile (independent of softmax) ----
    bf16x8 vf[16];
    {
      const unsigned short* vp = vb + (size_t)lo * SKV + tb + g * 8;
#pragma unroll
      for (int dt = 0; dt < 8; ++dt) {
        vf[dt * 2]     = *reinterpret_cast<const bf16x8*>(vp + (size_t)dt * 16 * SKV);
        vf[dt * 2 + 1] = *reinterpret_cast<const bf16x8*>(vp + (size_t)dt * 16 * SKV + 32);
      }
    }

    // ---- mask invalid upper half of odd-count last tile ----
    if (odd && t == n64 - 1) {
      s[2] = (f32x4){-1e30f, -1e30f, -1e30f, -1e30f};
      s[3] = (f32x4){-1e30f, -1e30f, -1e30f, -1e30f};
    }

    // ---- online softmax: 16 in-lane values + 2 shfl (cross-g) ----
    float pmax = fmaxf(fmaxf(fmaxf(s[0][0], s[0][1]), fmaxf(s[0][2], s[0][3])),
                       fmaxf(fmaxf(s[1][0], s[1][1]), fmaxf(s[1][2], s[1][3])));
    pmax = fmaxf(pmax,
                 fmaxf(fmaxf(fmaxf(s[2][0], s[2][1]), fmaxf(s[2][2], s[2][3])),
                       fmaxf(fmaxf(s[3][0], s[3][1]), fmaxf(s[3][2], s[3][3]))));
    pmax = fmaxf(pmax, __shfl_xor(pmax, 16));
    pmax = fmaxf(pmax, __shfl_xor(pmax, 32));

    // defer-max (THR=8 in log2 units -> P bounded by 256)
    if (!__all(pmax - m <= 8.f)) {
      float mn = fmaxf(m, pmax);
      float scl = __builtin_amdgcn_exp2f(m - mn);
      lsum *= scl;
#pragma unroll
      for (int dt = 0; dt < 8; ++dt) {
        acc[dt][0] *= scl; acc[dt][1] *= scl;
        acc[dt][2] *= scl; acc[dt][3] *= scl;
      }
      m = mn;
    }

    float rs = 0.f;
    u16x4 pk[4];
#pragma unroll
    for (int sf = 0; sf < 4; ++sf) {
#pragma unroll
      for (int r = 0; r < 4; ++r) {
        float p = __builtin_amdgcn_exp2f(s[sf][r] - m);
        rs += p;
        pk[sf][r] = f2bf(p);
      }
    }
    rs += __shfl_xor(rs, 16);
    rs += __shfl_xor(rs, 32);
    lsum += rs;

    // ---- P transpose through per-wave LDS (no barrier) ----
#pragma unroll
    for (int sf = 0; sf < 4; ++sf)
      *reinterpret_cast<u16x4*>(&p_lds[wid][lo][sf * 16 + g * 4]) = pk[sf];
    bf16x8 pf0 = *reinterpret_cast<const bf16x8*>(&p_lds[wid][lo][g * 8]);
    bf16x8 pf1 = *reinterpret_cast<const bf16x8*>(&p_lds[wid][lo][32 + g * 8]);

    // ---- PV ----
#pragma unroll
    for (int dt = 0; dt < 8; ++dt) {
      acc[dt] = mfma16(pf0, vf[dt * 2], acc[dt]);
      acc[dt] = mfma16(pf1, vf[dt * 2 + 1], acc[dt]);
    }

#pragma unroll
    for (int i = 0; i < 16; ++i) kf[i] = kn[i];
  }

  // ---- epilogue: broadcast denom to C-layout rows, normalize, store ----
#pragma unroll
  for (int r = 0; r < 4; ++r) {
    int src = (l & 48) | (g * 4 + r);
    float inv = 1.f / __shfl(lsum, src);
    float* op = out + (size_t)(qbase + g * 4 + r) * (H * D) + hq * D + lo;
#pragma unroll
    for (int dt = 0; dt < 8; ++dt) op[dt * 16] = acc[dt][r] * inv;
  }
}

extern "C" void kernel_launch(void* const* d_in, const int* in_sizes, int n_in,
                              void* d_out, int out_size, void* d_ws, size_t ws_size,
                              hipStream_t stream) {
  (void)in_sizes; (void)n_in; (void)out_size; (void)ws_size;
  const float* q = (const float*)d_in[0];
  const float* k = (const float*)d_in[1];
  const float* v = (const float*)d_in[2];
  const float* k_cache = (const float*)d_in[3];
  const float* v_cache = (const float*)d_in[4];
  const int* cache_slots = (const int*)d_in[6];
  float* out = (float*)d_out;

  float* scales = (float*)d_ws;                                   // 16 floats
  unsigned short* k_comb = (unsigned short*)((char*)d_ws + 256);  // 8 MB
  unsigned short* v_combT = k_comb + (size_t)HKV * SKV * D;       // 8 MB

  scales_kernel<<<16, 256, 0, stream>>>(k, v, scales);
  prep_k<<<2048, 256, 0, stream>>>(k, k_cache, cache_slots, scales, k_comb);
  prep_v<<<2048, 256, 0, stream>>>(v, v_cache, cache_slots, scales, v_combT);
  attn_kernel<<<512, 256, 0, stream>>>(q, k_comb, v_combT, out);
}

// Round 4
// 455.891 us; speedup vs baseline: 1.0980x; 1.0229x over previous
//
#include <hip/hip_runtime.h>
#include <stdint.h>

#define H 32
#define HKV 8
#define D 128
#define SQ 1024
#define CTX 3072
#define SKV 4096
#define FP8_MAX_C 448.0f
#define EPS_C 1e-8f

typedef __attribute__((ext_vector_type(4))) float f32x4;
typedef __attribute__((ext_vector_type(8))) __bf16 bf16x8;
typedef __attribute__((ext_vector_type(8))) unsigned short u16x8;
typedef __attribute__((ext_vector_type(4))) unsigned short u16x4;

__device__ __forceinline__ unsigned short f2bf(float x) {
  unsigned int u = __builtin_bit_cast(unsigned int, x);
  u += 0x7fffu + ((u >> 16) & 1u);
  return (unsigned short)(u >> 16);
}

__device__ __forceinline__ f32x4 mfma16(bf16x8 a, bf16x8 b, f32x4 c) {
  return __builtin_amdgcn_mfma_f32_16x16x32_bf16(a, b, c, 0, 0, 0);
}

// ---- scales stage 1: partial absmax -> atomicMax on float bits ----
__global__ void scales_part(const float* __restrict__ k,
                            const float* __restrict__ v,
                            unsigned int* __restrict__ smax) {
  const int b = blockIdx.x & 15;    // 0..7 k-heads, 8..15 v-heads
  const int part = blockIdx.x >> 4; // 0..7
  const float* src = (b < HKV) ? k : v;
  const int h = b & 7;
  const int tid = threadIdx.x;  // 256
  const int d0 = (tid & 31) * 4;
  float mx = 0.f;
  const int t1 = part * 128 + 128;
  for (int t = part * 128 + (tid >> 5); t < t1; t += 8) {
    float4 vv = *reinterpret_cast<const float4*>(src + (size_t)t * (HKV * D) + h * D + d0);
    mx = fmaxf(mx, fmaxf(fmaxf(fabsf(vv.x), fabsf(vv.y)),
                         fmaxf(fabsf(vv.z), fabsf(vv.w))));
  }
  __shared__ float red[256];
  red[tid] = mx;
  __syncthreads();
  for (int s = 128; s > 0; s >>= 1) {
    if (tid < s) red[tid] = fmaxf(red[tid], red[tid + s]);
    __syncthreads();
  }
  if (tid == 0) atomicMax(&smax[b], __float_as_uint(red[0]));
}

// ---- scales stage 2: finalize ----
__global__ void scales_fin(const unsigned int* __restrict__ smax,
                           float* __restrict__ scales) {
  const int i = threadIdx.x;
  if (i < 16) scales[i] = fmaxf(__uint_as_float(smax[i]) / FP8_MAX_C, EPS_C);
}

// ---- prep k_comb[h][t][d] bf16 ----
__global__ void prep_k(const float* __restrict__ k,
                       const float* __restrict__ k_cache,
                       const int* __restrict__ cache_slots,
                       const float* __restrict__ scales,
                       unsigned short* __restrict__ k_comb) {
  const int tid = blockIdx.x * 256 + threadIdx.x;  // 524288
  const int d8 = tid & 15;
  const int t = (tid >> 4) & (SKV - 1);
  const int h = tid >> 16;
  const int d0 = d8 * 8;
  const float* src;
  float mul;
  if (t < CTX) {
    int slot = cache_slots[t];
    src = k_cache + (size_t)slot * (HKV * D) + h * D + d0;
    mul = scales[h];
  } else {
    src = k + (size_t)(t - CTX) * (HKV * D) + h * D + d0;
    mul = 1.f;
  }
  float4 a = *reinterpret_cast<const float4*>(src);
  float4 bb = *reinterpret_cast<const float4*>(src + 4);
  u16x8 r;
  r[0] = f2bf(a.x * mul);  r[1] = f2bf(a.y * mul);
  r[2] = f2bf(a.z * mul);  r[3] = f2bf(a.w * mul);
  r[4] = f2bf(bb.x * mul); r[5] = f2bf(bb.y * mul);
  r[6] = f2bf(bb.z * mul); r[7] = f2bf(bb.w * mul);
  *reinterpret_cast<u16x8*>(k_comb + ((size_t)h * SKV + t) * D + d0) = r;
}

// ---- prep v_combT[h][d][t] bf16 ----
__global__ void prep_v(const float* __restrict__ v,
                       const float* __restrict__ v_cache,
                       const int* __restrict__ cache_slots,
                       const float* __restrict__ scales,
                       unsigned short* __restrict__ v_combT) {
  const int tid = blockIdx.x * 256 + threadIdx.x;  // 524288
  const int d = tid & 127;
  const int t8 = (tid >> 7) & 511;
  const int h = tid >> 16;
  const int t0 = t8 * 8;
  const float sc = scales[8 + h];
  u16x8 r;
#pragma unroll
  for (int i = 0; i < 8; ++i) {
    int t = t0 + i;
    float val;
    if (t < CTX) {
      int slot = cache_slots[t];
      val = v_cache[(size_t)slot * (HKV * D) + h * D + d] * sc;
    } else {
      val = v[(size_t)(t - CTX) * (HKV * D) + h * D + d];
    }
    r[i] = f2bf(val);
  }
  *reinterpret_cast<u16x8*>(v_combT + ((size_t)h * D + d) * SKV + t0) = r;
}

#define LDBF(p) (*reinterpret_cast<const bf16x8*>(p))

// ---- flash attention: swapped QK^T, KVBLK=64, spill-free, lazy softmax ----
__launch_bounds__(256, 2)
__global__ void attn_kernel(const float* __restrict__ q,
                            const unsigned short* __restrict__ k_comb,
                            const unsigned short* __restrict__ v_combT,
                            float* __restrict__ out) {
  const int bid = blockIdx.x;
  const int hkv = bid & 7;   // XCD-aware: one kv-head per XCD -> K/V L2-resident
  const int qt = bid >> 3;   // 0..63
  const int wid = threadIdx.x >> 6;
  const int l = threadIdx.x & 63;
  const int lo = l & 15;
  const int g = l >> 4;
  const int hq = hkv * 4 + wid;
  const int qbase = qt * 16;
  const int nt32 = 97 + (qt >> 1);
  const int n64 = (nt32 + 1) >> 1;
  const bool odd = (nt32 & 1) != 0;

  // Q fragments (B-operand), pre-scaled by SCALE*log2(e) for exp2 softmax
  bf16x8 qf[4];
  {
    const float qs = 0.088388347648318447f * 1.4426950408889634f;
    const float* qp = q + (size_t)(qbase + lo) * (H * D) + hq * D;
#pragma unroll
    for (int ks = 0; ks < 4; ++ks) {
      int d0 = ks * 32 + g * 8;
      float4 a = *reinterpret_cast<const float4*>(qp + d0);
      float4 b = *reinterpret_cast<const float4*>(qp + d0 + 4);
      union { unsigned short u[8]; bf16x8 v; } f;
      f.u[0] = f2bf(a.x * qs); f.u[1] = f2bf(a.y * qs);
      f.u[2] = f2bf(a.z * qs); f.u[3] = f2bf(a.w * qs);
      f.u[4] = f2bf(b.x * qs); f.u[5] = f2bf(b.y * qs);
      f.u[6] = f2bf(b.z * qs); f.u[7] = f2bf(b.w * qs);
      qf[ks] = f.v;
    }
  }

  f32x4 acc[8];
#pragma unroll
  for (int dt = 0; dt < 8; ++dt) acc[dt] = (f32x4){0.f, 0.f, 0.f, 0.f};
  float m = -1e30f;   // running row max (log2 units); row = lo
  float lsum = 0.f;   // per-lane PARTIAL denom (reduced in epilogue)

  // per-wave P bounce buffer: [q=16][kv=64] padded to 72
  __shared__ __align__(16) unsigned short p_lds[4][16][72];

  const unsigned short* kb = k_comb + (size_t)hkv * SKV * D;
  const unsigned short* vb = v_combT + (size_t)hkv * D * SKV;

  // prologue: K tile 0 into kf (no lambdas -> stays in VGPRs)
  bf16x8 kf[16];
  {
    const unsigned short* kp = kb + (size_t)lo * D + g * 8;
#pragma unroll
    for (int sf = 0; sf < 4; ++sf)
#pragma unroll
      for (int ks = 0; ks < 4; ++ks)
        kf[sf * 4 + ks] = LDBF(kp + (size_t)sf * 16 * D + ks * 32);
  }

  for (int t = 0; t < n64; ++t) {
    const int tb = t * 64;

    // ---- issue V loads first (latency hides under QK) ----
    bf16x8 vf[16];
    {
      const unsigned short* vp = vb + (size_t)lo * SKV + tb + g * 8;
#pragma unroll
      for (int dt = 0; dt < 8; ++dt) {
        vf[dt * 2]     = LDBF(vp + (size_t)dt * 16 * SKV);
        vf[dt * 2 + 1] = LDBF(vp + (size_t)dt * 16 * SKV + 32);
      }
    }

    // ---- QK^T swapped: s[sf] = S^T[kv rows][q cols] ----
    f32x4 s[4];
#pragma unroll
    for (int sf = 0; sf < 4; ++sf) {
      s[sf] = (f32x4){0.f, 0.f, 0.f, 0.f};
#pragma unroll
      for (int ks = 0; ks < 4; ++ks)
        s[sf] = mfma16(kf[sf * 4 + ks], qf[ks], s[sf]);
    }

    // ---- prefetch next K tile IN PLACE (kf dead after QK).
    // Always issued; final-iter overreach lands in v_combT (allocated). ----
    {
      const unsigned short* kp = kb + (size_t)(tb + 64 + lo) * D + g * 8;
#pragma unroll
      for (int sf = 0; sf < 4; ++sf)
#pragma unroll
        for (int ks = 0; ks < 4; ++ks)
          kf[sf * 4 + ks] = LDBF(kp + (size_t)sf * 16 * D + ks * 32);
    }

    // ---- mask invalid upper half of odd-count last tile ----
    if (odd && t == n64 - 1) {
      s[2] = (f32x4){-1e30f, -1e30f, -1e30f, -1e30f};
      s[3] = (f32x4){-1e30f, -1e30f, -1e30f, -1e30f};
    }

    // ---- lazy online softmax: NO cross-lane ops in the common path ----
    float pmax = fmaxf(fmaxf(fmaxf(s[0][0], s[0][1]), fmaxf(s[0][2], s[0][3])),
                       fmaxf(fmaxf(s[1][0], s[1][1]), fmaxf(s[1][2], s[1][3])));
    pmax = fmaxf(pmax,
                 fmaxf(fmaxf(fmaxf(s[2][0], s[2][1]), fmaxf(s[2][2], s[2][3])),
                       fmaxf(fmaxf(s[3][0], s[3][1]), fmaxf(s[3][2], s[3][3]))));
    if (!__all(pmax - m <= 8.f)) {  // rescale path (rare after warm-up)
      float rm = fmaxf(pmax, __shfl_xor(pmax, 16));
      rm = fmaxf(rm, __shfl_xor(rm, 32));
      float mn = fmaxf(m, rm);
      float scl = __builtin_amdgcn_exp2f(m - mn);
      lsum *= scl;
#pragma unroll
      for (int dt = 0; dt < 8; ++dt) {
        acc[dt][0] *= scl; acc[dt][1] *= scl;
        acc[dt][2] *= scl; acc[dt][3] *= scl;
      }
      m = mn;
    }

    float rs = 0.f;
    u16x4 pk[4];
#pragma unroll
    for (int sf = 0; sf < 4; ++sf) {
#pragma unroll
      for (int r = 0; r < 4; ++r) {
        float p = __builtin_amdgcn_exp2f(s[sf][r] - m);
        rs += p;
        pk[sf][r] = f2bf(p);
      }
    }
    lsum += rs;  // per-lane partial; row sum deferred to epilogue

    // ---- P transpose through per-wave LDS (no barrier; 2-way conflicts) ----
#pragma unroll
    for (int sf = 0; sf < 4; ++sf)
      *reinterpret_cast<u16x4*>(&p_lds[wid][lo][sf * 16 + g * 4]) = pk[sf];
    bf16x8 pf0 = LDBF(&p_lds[wid][lo][g * 8]);
    bf16x8 pf1 = LDBF(&p_lds[wid][lo][32 + g * 8]);

    // ---- PV ----
#pragma unroll
    for (int dt = 0; dt < 8; ++dt) {
      acc[dt] = mfma16(pf0, vf[dt * 2], acc[dt]);
      acc[dt] = mfma16(pf1, vf[dt * 2 + 1], acc[dt]);
    }
  }

  // ---- epilogue: reduce denom, broadcast to C-layout rows, store ----
  lsum += __shfl_xor(lsum, 16);
  lsum += __shfl_xor(lsum, 32);
#pragma unroll
  for (int r = 0; r < 4; ++r) {
    int src = (l & 48) | (g * 4 + r);
    float inv = 1.f / __shfl(lsum, src);
    float* op = out + (size_t)(qbase + g * 4 + r) * (H * D) + hq * D + lo;
#pragma unroll
    for (int dt = 0; dt < 8; ++dt) op[dt * 16] = acc[dt][r] * inv;
  }
}

extern "C" void kernel_launch(void* const* d_in, const int* in_sizes, int n_in,
                              void* d_out, int out_size, void* d_ws, size_t ws_size,
                              hipStream_t stream) {
  (void)in_sizes; (void)n_in; (void)out_size; (void)ws_size;
  const float* q = (const float*)d_in[0];
  const float* k = (const float*)d_in[1];
  const float* v = (const float*)d_in[2];
  const float* k_cache = (const float*)d_in[3];
  const float* v_cache = (const float*)d_in[4];
  const int* cache_slots = (const int*)d_in[6];
  float* out = (float*)d_out;

  unsigned int* smax = (unsigned int*)d_ws;                       // 16 u32
  float* scales = (float*)((char*)d_ws + 64);                     // 16 floats
  unsigned short* k_comb = (unsigned short*)((char*)d_ws + 256);  // 8 MB
  unsigned short* v_combT = k_comb + (size_t)HKV * SKV * D;       // 8 MB

  hipMemsetAsync(smax, 0, 64, stream);
  scales_part<<<128, 256, 0, stream>>>(k, v, smax);
  scales_fin<<<1, 64, 0, stream>>>(smax, scales);
  prep_k<<<2048, 256, 0, stream>>>(k, k_cache, cache_slots, scales, k_comb);
  prep_v<<<2048, 256, 0, stream>>>(v, v_cache, cache_slots, scales, v_combT);
  attn_kernel<<<512, 256, 0, stream>>>(q, k_comb, v_combT, out);
}